// Round 7
// baseline (947.835 us; speedup 1.0000x reference)
//
#include <hip/hip_runtime.h>
#include <hip/hip_bf16.h>

// DPMultiHeadAttention MI355X — Round 7.
// R6 post-mortem: attention latency-bound (no pipe saturated; 2 blk/CU, long dep chains).
// R7: (1) Q hi-only in QK (8 MFMA/iter, 4-deep chains, no ql array);
//     (2) split-K x2 across blocks: grid (16,32,2)=1024 blocks=4/CU, fp32 O/l partials,
//         pure-sum merge (no-max softmax) in new streaming merge_ctx kernel;
//     (3) single-buffer 32KB staging -> 38KB block LDS -> 4 blocks/CU;
//     (4) ws high-water 65.3MB (<= proven 67MB): Op0 overlays xh/xl, cth/ctl overlay khF/vhF.

constexpr int B  = 2;
constexpr int S  = 2048;
constexpr int D  = 1024;
constexpr int H  = 16;
constexpr int DH = 64;
constexpr int BS = B * S;   // 4096

using u16 = unsigned short;
using u32 = unsigned int;
using frag8  = __attribute__((ext_vector_type(8)))  short;
using f32x4  = __attribute__((ext_vector_type(4)))  float;
using f32x16 = __attribute__((ext_vector_type(16))) float;

__device__ inline u16 f2bf(float x) {
    u32 u = __float_as_uint(x);
    return (u16)((u + 0x7FFF + ((u >> 16) & 1)) >> 16);
}
__device__ inline u32 pk2(float a, float b) {   // v_cvt_pk_bf16_f32
    __hip_bfloat162 t = __float22bfloat162_rn(make_float2(a, b));
    union { __hip_bfloat162 h; u32 u; } c; c.h = t; return c.u;
}
__device__ inline float unpk_lo(u32 p) { return __uint_as_float(p << 16); }
__device__ inline float unpk_hi(u32 p) { return __uint_as_float(p & 0xffff0000u); }

__device__ inline void glds16(const u16* g, const u16* l) {
    __builtin_amdgcn_global_load_lds(
        (const __attribute__((address_space(1))) void*)g,
        (__attribute__((address_space(3))) void*)l, 16, 0, 0);
}

// score scale: 1/sqrt(DH) * log2(e) (exp2-domain softmax), folded into K
#define KSC (0.125f * 1.44269504088896f)

// ---------------------------------------------------------------------------
// convert_x: x fp32 [4096][1024] -> xh, xl (split bf16)
// ---------------------------------------------------------------------------
__global__ __launch_bounds__(256) void convert_x(
    const float* __restrict__ x, u16* __restrict__ xh, u16* __restrict__ xl)
{
    const size_t idx = ((size_t)blockIdx.x * 256 + threadIdx.x) * 4;
    float4 v = *(const float4*)&x[idx];
    u32 h01 = pk2(v.x, v.y), h23 = pk2(v.z, v.w);
    *(uint2*)&xh[idx] = make_uint2(h01, h23);
    *(uint2*)&xl[idx] = make_uint2(pk2(v.x - unpk_lo(h01), v.y - unpk_hi(h01)),
                                   pk2(v.z - unpk_lo(h23), v.w - unpk_hi(h23)));
}

// ---------------------------------------------------------------------------
// transpose_w: Wt[4096][1024] bf16, k-contiguous rows.
// rows [0,3072): Wt[(t*16+h)*64+e][k] = W_t[h][k][e]; rows [3072,4096): Wo^T.
// ---------------------------------------------------------------------------
__global__ __launch_bounds__(256) void transpose_w(
    const float* __restrict__ Wq, const float* __restrict__ Wk,
    const float* __restrict__ Wv, const float* __restrict__ Wo,
    u16* __restrict__ Wt)
{
    const int kt = blockIdx.x;      // 0..15
    const int sl = blockIdx.y;      // 0..63
    const int tid = threadIdx.x;
    __shared__ float Ls[64][68];

    const float* src; int rstride;
    if (sl < 48) {
        const int t = sl >> 4, h = sl & 15;
        const float* Wp = (t == 0) ? Wq : ((t == 1) ? Wk : Wv);
        src = Wp + (size_t)h * D * DH;
        rstride = 64;
    } else {
        src = Wo + (sl - 48) * 64;
        rstride = 1024;
    }

    const int rr = tid >> 4, c4 = tid & 15;
#pragma unroll
    for (int p = 0; p < 4; ++p) {
        const int kk = p * 16 + rr;
        float4 v = *(const float4*)&src[(size_t)(kt * 64 + kk) * rstride + c4 * 4];
        *(float4*)&Ls[kk][c4 * 4] = v;
    }
    __syncthreads();
    const int rl = tid >> 2, ks = tid & 3;
    u16 ob[16];
#pragma unroll
    for (int i = 0; i < 16; ++i) ob[i] = f2bf(Ls[ks * 16 + i][rl]);
    u16* dst = Wt + (size_t)(sl * 64 + rl) * 1024 + kt * 64 + ks * 16;
    *(uint4*)&dst[0] = *(uint4*)&ob[0];
    *(uint4*)&dst[8] = *(uint4*)&ob[8];
}

// ---------------------------------------------------------------------------
// gemm_qkv: C[n][s] = sum_k Wt[n,k]*x[s,k]. A=Wt rounded, B=xh+xl split.
// 128x128 tile, 64 MFMA per barrier pair. grid (24,32).
// Epilogue: q -> qh row-major [bh][s][64] (hi only); k -> khF (scaled KSC);
//           v -> vhF. Fragment granule per (bh,kt): off = ((sub*4+ks)*64+lane)*8+j
// ---------------------------------------------------------------------------
__global__ __launch_bounds__(256, 3) void gemm_qkv(
    const u16* __restrict__ Wt, const u16* __restrict__ xh, const u16* __restrict__ xl,
    const float* __restrict__ bq, const float* __restrict__ bk, const float* __restrict__ bv,
    u16* __restrict__ qhO, u16* __restrict__ khF, u16* __restrict__ vhF)
{
    const int r0  = blockIdx.x * 128;     // n
    const int c0  = blockIdx.y * 128;     // s
    const int tid = threadIdx.x;
    const int w = tid >> 6, lane = tid & 63;
    const int wi = w >> 1, wj = w & 1;
    const int ml = lane & 15, kg = lane >> 4;

    __shared__ u16 Ta[2][128 * 32];
    __shared__ u16 Tb[2][128 * 32];
    __shared__ u16 Tl[2][128 * 32];

    const int srow = lane >> 2, sseg = lane & 3;
    const u16* Ag = Wt + (size_t)(r0 + w * 32 + srow) * 1024 + sseg * 8;
    const u16* Bg = xh + (size_t)(c0 + w * 32 + srow) * 1024 + sseg * 8;
    const u16* Lg = xl + (size_t)(c0 + w * 32 + srow) * 1024 + sseg * 8;

    f32x4 acc[4][4];
#pragma unroll
    for (int i = 0; i < 4; ++i)
#pragma unroll
        for (int j = 0; j < 4; ++j)
#pragma unroll
            for (int r = 0; r < 4; ++r) acc[i][j][r] = 0.f;

    for (int k0 = 0; k0 < 1024; k0 += 64) {
        __syncthreads();
#pragma unroll
        for (int hb = 0; hb < 2; ++hb) {
            const int ko = k0 + hb * 32;
            glds16(Ag + ko,             &Ta[hb][(w * 32) * 32]);
            glds16(Ag + 16 * 1024 + ko, &Ta[hb][(w * 32 + 16) * 32]);
            glds16(Bg + ko,             &Tb[hb][(w * 32) * 32]);
            glds16(Bg + 16 * 1024 + ko, &Tb[hb][(w * 32 + 16) * 32]);
            glds16(Lg + ko,             &Tl[hb][(w * 32) * 32]);
            glds16(Lg + 16 * 1024 + ko, &Tl[hb][(w * 32 + 16) * 32]);
        }
        __syncthreads();

#pragma unroll
        for (int hb = 0; hb < 2; ++hb) {
            frag8 af[4], bf[4], lf[4];
#pragma unroll
            for (int i = 0; i < 4; ++i)
                af[i] = *(const frag8*)&Ta[hb][(wi * 64 + i * 16 + ml) * 32 + kg * 8];
#pragma unroll
            for (int j = 0; j < 4; ++j) {
                bf[j] = *(const frag8*)&Tb[hb][(wj * 64 + j * 16 + ml) * 32 + kg * 8];
                lf[j] = *(const frag8*)&Tl[hb][(wj * 64 + j * 16 + ml) * 32 + kg * 8];
            }
#pragma unroll
            for (int i = 0; i < 4; ++i)
#pragma unroll
                for (int j = 0; j < 4; ++j) {
                    acc[i][j] = __builtin_amdgcn_mfma_f32_16x16x32_bf16(af[i], bf[j], acc[i][j], 0, 0, 0);
                    acc[i][j] = __builtin_amdgcn_mfma_f32_16x16x32_bf16(af[i], lf[j], acc[i][j], 0, 0, 0);
                }
        }
    }

    // epilogue: C/D col = ml (s), rows = n
    const int t = r0 >> 10;                      // 0:q 1:k 2:v
    if (t == 0) {
#pragma unroll
        for (int i = 0; i < 4; ++i) {
            const int Rb = r0 + wi * 64 + i * 16 + kg * 4;
            const int h  = (Rb >> 6) & 15;
            const int e0 = Rb & 63;
            float bv4[4];
#pragma unroll
            for (int r = 0; r < 4; ++r) bv4[r] = bq[(Rb & 1023) + r];
#pragma unroll
            for (int j = 0; j < 4; ++j) {
                const int s  = c0 + wj * 64 + j * 16 + ml;
                const int bb = s >> 11, sl = s & (S - 1);
                float v[4];
#pragma unroll
                for (int r = 0; r < 4; ++r) v[r] = acc[i][j][r] + bv4[r];
                const size_t base = ((size_t)(bb * H + h) * S + sl) * 64 + e0;
                *(uint2*)&qhO[base] = make_uint2(pk2(v[0], v[1]), pk2(v[2], v[3]));
            }
        }
    } else if (t == 1) {
#pragma unroll
        for (int i = 0; i < 4; ++i) {
            const int Rb = r0 + wi * 64 + i * 16 + kg * 4;
            const int h  = (Rb >> 6) & 15;
            const int e0 = Rb & 63;
            const int ksf = e0 >> 4, Hf = (e0 >> 3) & 1, j0 = e0 & 7;
            float bv4[4];
#pragma unroll
            for (int r = 0; r < 4; ++r) bv4[r] = bk[(Rb & 1023) + r];
#pragma unroll
            for (int j = 0; j < 4; ++j) {
                const int s  = c0 + wj * 64 + j * 16 + ml;
                const int bb = s >> 11, sl = s & (S - 1);
                const int bh = bb * H + h;
                const int kt = sl >> 6, sub = (sl >> 5) & 1, klow = sl & 31;
                const int lanef = klow | (Hf << 5);
                const size_t off = (size_t)bh * 131072 +
                    (size_t)(((kt * 2 + sub) * 4 + ksf) * 64 + lanef) * 8 + j0;
                float v[4];
#pragma unroll
                for (int r = 0; r < 4; ++r) v[r] = (acc[i][j][r] + bv4[r]) * KSC;
                *(uint2*)&khF[off] = make_uint2(pk2(v[0], v[1]), pk2(v[2], v[3]));
            }
        }
    } else {
#pragma unroll
        for (int i = 0; i < 4; ++i) {
            const int Rb  = r0 + wi * 64 + i * 16 + kg * 4;
            const int h   = (Rb >> 6) & 15;
            const int dh0 = Rb & 63;
            float bv4[4];
#pragma unroll
            for (int r = 0; r < 4; ++r) bv4[r] = bv[(Rb & 1023) + r];
#pragma unroll
            for (int j = 0; j < 4; ++j) {
                const int s  = c0 + wj * 64 + j * 16 + ml;
                const int bb = s >> 11, sl = s & (S - 1);
                const int bh = bb * H + h;
                const int kt = sl >> 6, key = sl & 63;
                const int ksf = key >> 4, Hf = (key >> 3) & 1, j0 = key & 7;
                const size_t tb = (size_t)bh * 131072 + (size_t)j0 +
                                  (size_t)((kt * 2) * 4 + ksf) * 512;
#pragma unroll
                for (int r = 0; r < 4; ++r) {
                    const int dh = dh0 + r;
                    const int sub = dh >> 5;
                    const int lanef = (dh & 31) | (Hf << 5);
                    vhF[tb + (size_t)sub * 2048 + (size_t)lanef * 8] =
                        f2bf(acc[i][j][r] + bv4[r]);
                }
            }
        }
    }
}

// ---------------------------------------------------------------------------
// attention: split-K x2 across blocks + x2 in-block. grid (16, 32, 2).
// Block: 512 thr = 2 groups x 4 waves; part p group g handles keys
// [(p*2+g)*512, +512) for the same 128 q rows (8 iters of 64 keys).
// No-max exp2 softmax; Q hi-only (8 QK MFMA/iter). Writes UNNORMALIZED fp32
// O-partial [p][bh][s][64] + l-partial [p][bh][s]; merge_ctx combines.
// ---------------------------------------------------------------------------
__global__ __launch_bounds__(512, 6) void attention_mfma(
    const u16* __restrict__ qh, const u16* __restrict__ khF,
    const u16* __restrict__ vhF,
    float* __restrict__ Op0, float* __restrict__ Op1,
    float* __restrict__ lpart)
{
    const int qt  = blockIdx.x;      // 0..15
    const int bh  = blockIdx.y;      // 0..31
    const int p   = blockIdx.z;      // 0..1
    const int tid = threadIdx.x;
    const int w   = tid >> 6, wl = w & 3, g = w >> 2;
    const int lane = tid & 63;
    const int nq  = lane & 31;
    const int Hh  = lane >> 5;

    __shared__ union {
        u16   stg[2][2][4096];   // [group][K,V][64keys x 64dh] = 32KB single buf
        float xch[128][72];      // merge/output buffer 36.9KB
    } L;
    __shared__ float lsum[2][128];

    // Q fragments hi (B-operand), register resident: dh = ks*16 + Hh*8 + j
    const int qrow = qt * 128 + wl * 32 + nq;
    const u16* qhp = qh + ((size_t)bh * S + qrow) * DH;
    frag8 qf[4];
#pragma unroll
    for (int ks = 0; ks < 4; ++ks) qf[ks] = *(const frag8*)(qhp + ks * 16 + Hh * 8);

    f32x16 O0, O1;
#pragma unroll
    for (int i = 0; i < 16; ++i) { O0[i] = 0.f; O1[i] = 0.f; }
    float l_run = 0.f;

    const int go = wl * 1024 + lane * 8;
    const size_t bhb = (size_t)bh * 131072;
    u16* sK = &L.stg[g][0][0];
    u16* sV = &L.stg[g][1][0];

    for (int it = 0; it < 8; ++it) {
        const size_t kb = bhb + (size_t)((p * 2 + g) * 8 + it) * 4096;
        __syncthreads();                 // prior reads of stg done
        glds16(khF + kb + go,       sK + wl * 1024);
        glds16(khF + kb + go + 512, sK + wl * 1024 + 512);
        glds16(vhF + kb + go,       sV + wl * 1024);
        glds16(vhF + kb + go + 512, sV + wl * 1024 + 512);
        __syncthreads();                 // loads complete (vmcnt drain)

        // ---- S^T = K·Q^T  (K rounded+scaled; Q hi only)
        f32x16 sa0, sa1;
#pragma unroll
        for (int i = 0; i < 16; ++i) { sa0[i] = 0.f; sa1[i] = 0.f; }
#pragma unroll
        for (int ks = 0; ks < 4; ++ks) {
            frag8 k0 = *(const frag8*)&sK[(ks * 64 + lane) * 8];
            frag8 k1 = *(const frag8*)&sK[((4 + ks) * 64 + lane) * 8];
            sa0 = __builtin_amdgcn_mfma_f32_32x32x16_bf16(k0, qf[ks], sa0, 0, 0, 0);
            sa1 = __builtin_amdgcn_mfma_f32_32x32x16_bf16(k1, qf[ks], sa1, 0, 0, 0);
        }

        // ---- no-max softmax numerators
        float psum = 0.f;
        u32 ph0[8], ph1[8];
#pragma unroll
        for (int u = 0; u < 8; ++u) {
            float e0 = exp2f(sa0[2 * u]);
            float e1 = exp2f(sa0[2 * u + 1]);
            float f0 = exp2f(sa1[2 * u]);
            float f1 = exp2f(sa1[2 * u + 1]);
            psum += (e0 + e1) + (f0 + f1);
            ph0[u] = pk2(e0, e1);
            ph1[u] = pk2(f0, f1);
        }
        l_run += psum;

        // ---- O^T += V^T · P^T  (P^T B-frags via half-swap shuffles)
#pragma unroll
        for (int ks = 0; ks < 4; ++ks) {
            const u32* PH = (ks < 2) ? ph0 : ph1;
            const int ks2 = ks & 1;
            const int oi = 4 * ks2 + 2 * Hh;
            const int si = 4 * ks2 + 2 * (1 - Hh);
            u32 rh0 = __shfl_xor(PH[si], 32), rh1 = __shfl_xor(PH[si + 1], 32);
            union { u32 u[4]; frag8 f; } fh;
            if (Hh == 0) {
                fh.u[0] = PH[oi]; fh.u[1] = PH[oi + 1]; fh.u[2] = rh0; fh.u[3] = rh1;
            } else {
                fh.u[0] = rh0; fh.u[1] = rh1; fh.u[2] = PH[oi]; fh.u[3] = PH[oi + 1];
            }
            frag8 v0 = *(const frag8*)&sV[(ks * 64 + lane) * 8];
            frag8 v1 = *(const frag8*)&sV[((4 + ks) * 64 + lane) * 8];
            O0 = __builtin_amdgcn_mfma_f32_32x32x16_bf16(v0, fh.f, O0, 0, 0, 0);
            O1 = __builtin_amdgcn_mfma_f32_32x32x16_bf16(v1, fh.f, O1, 0, 0, 0);
        }
    }

    // ---- combine the two in-block groups (pure sums), write fp32 partial
    l_run += __shfl_xor(l_run, 32);
    const int qr = wl * 32 + nq;
    if (Hh == 0) lsum[g][qr] = l_run;
    __syncthreads();                     // stg reads done; union reuse safe

    if (g == 1) {
#pragma unroll
        for (int cdh = 0; cdh < 2; ++cdh)
#pragma unroll
            for (int rg = 0; rg < 4; ++rg) {
                const f32x16& O = cdh ? O1 : O0;
                float4 v4;
                v4.x = O[4 * rg + 0]; v4.y = O[4 * rg + 1];
                v4.z = O[4 * rg + 2]; v4.w = O[4 * rg + 3];
                *(float4*)&L.xch[qr][cdh * 32 + rg * 8 + Hh * 4] = v4;
            }
    }
    __syncthreads();
    if (g == 0) {
#pragma unroll
        for (int cdh = 0; cdh < 2; ++cdh)
#pragma unroll
            for (int rg = 0; rg < 4; ++rg) {
                float4 p4 = *(const float4*)&L.xch[qr][cdh * 32 + rg * 8 + Hh * 4];
                const f32x16& O = cdh ? O1 : O0;
                float4 v4;
                v4.x = O[4 * rg + 0] + p4.x;
                v4.y = O[4 * rg + 1] + p4.y;
                v4.z = O[4 * rg + 2] + p4.z;
                v4.w = O[4 * rg + 3] + p4.w;
                *(float4*)&L.xch[qr][cdh * 32 + rg * 8 + Hh * 4] = v4;
            }
    }
    __syncthreads();

    float* Op = p ? Op1 : Op0;
#pragma unroll
    for (int pass = 0; pass < 4; ++pass) {
        const int chunk = pass * 512 + tid;          // 0..2047
        const int qi = chunk >> 4, seg = chunk & 15;
        float4 v4 = *(const float4*)&L.xch[qi][seg * 4];
        *(float4*)&Op[((size_t)bh * S + qt * 128 + qi) * 64 + seg * 4] = v4;
    }
    if (tid < 128)
        lpart[((size_t)p * 32 + bh) * S + qt * 128 + tid] = lsum[0][tid] + lsum[1][tid];
}

// ---------------------------------------------------------------------------
// merge_ctx: ctx = (Op0 + Op1) / (l0 + l1), split-bf16 out. Streaming.
// idx over [bh][s][c4]: 32*2048*16 = 1,048,576 threads. grid 4096.
// ---------------------------------------------------------------------------
__global__ __launch_bounds__(256) void merge_ctx(
    const float* __restrict__ Op0, const float* __restrict__ Op1,
    const float* __restrict__ lp, u16* __restrict__ cth, u16* __restrict__ ctl)
{
    const int idx = blockIdx.x * 256 + threadIdx.x;
    const int bh = idx >> 15;
    const int r  = idx & 32767;
    const int s  = r >> 4, c4 = r & 15;
    const size_t ob = ((size_t)bh * S + s) * 64 + c4 * 4;
    float4 p0 = *(const float4*)&Op0[ob];
    float4 p1 = *(const float4*)&Op1[ob];
    const float inv = 1.f / (lp[(size_t)bh * S + s] + lp[(size_t)(32 + bh) * S + s]);
    float v0 = (p0.x + p1.x) * inv, v1 = (p0.y + p1.y) * inv;
    float v2 = (p0.z + p1.z) * inv, v3 = (p0.w + p1.w) * inv;
    u32 h01 = pk2(v0, v1), h23 = pk2(v2, v3);
    const int b = bh >> 4, h = bh & 15;
    const size_t base = ((size_t)(b * S + s)) * D + h * 64 + c4 * 4;
    *(uint2*)&cth[base] = make_uint2(h01, h23);
    *(uint2*)&ctl[base] = make_uint2(pk2(v0 - unpk_lo(h01), v1 - unpk_hi(h01)),
                                     pk2(v2 - unpk_lo(h23), v3 - unpk_hi(h23)));
}

// ---------------------------------------------------------------------------
// gemm_out: out[s][d] = sum_k ctx[s,k]*Wo[k,d] + bo. A=cth+ctl split, B=Wt+3072.
// 128x64 tile, grid (32,16).
// ---------------------------------------------------------------------------
__global__ __launch_bounds__(256, 4) void gemm_out(
    const u16* __restrict__ Ah, const u16* __restrict__ Al,
    const u16* __restrict__ Bh, const float* __restrict__ bo,
    float* __restrict__ out)
{
    const int r0  = blockIdx.x * 128;     // s
    const int c0  = blockIdx.y * 64;      // d
    const int tid = threadIdx.x;
    const int w = tid >> 6, lane = tid & 63;
    const int ml = lane & 15, kg = lane >> 4;

    __shared__ u16 Ta[2][128 * 32];
    __shared__ u16 Tl[2][128 * 32];
    __shared__ u16 Tb[2][64 * 32];

    const int srow = lane >> 2, sseg = lane & 3;
    const u16* Ag = Ah + (size_t)(r0 + w * 32 + srow) * 1024 + sseg * 8;
    const u16* Lg = Al + (size_t)(r0 + w * 32 + srow) * 1024 + sseg * 8;
    const u16* Bg = Bh + (size_t)(c0 + w * 16 + srow) * 1024 + sseg * 8;

    f32x4 acc[2][4];
#pragma unroll
    for (int i = 0; i < 2; ++i)
#pragma unroll
        for (int j = 0; j < 4; ++j)
#pragma unroll
            for (int r = 0; r < 4; ++r) acc[i][j][r] = 0.f;

    for (int k0 = 0; k0 < 1024; k0 += 64) {
        __syncthreads();
#pragma unroll
        for (int hb = 0; hb < 2; ++hb) {
            const int ko = k0 + hb * 32;
            glds16(Ag + ko,             &Ta[hb][(w * 32) * 32]);
            glds16(Ag + 16 * 1024 + ko, &Ta[hb][(w * 32 + 16) * 32]);
            glds16(Lg + ko,             &Tl[hb][(w * 32) * 32]);
            glds16(Lg + 16 * 1024 + ko, &Tl[hb][(w * 32 + 16) * 32]);
            glds16(Bg + ko,             &Tb[hb][(w * 16) * 32]);
        }
        __syncthreads();

#pragma unroll
        for (int hb = 0; hb < 2; ++hb) {
            frag8 af[2], lf[2], bf[4];
#pragma unroll
            for (int i = 0; i < 2; ++i) {
                af[i] = *(const frag8*)&Ta[hb][(w * 32 + i * 16 + ml) * 32 + kg * 8];
                lf[i] = *(const frag8*)&Tl[hb][(w * 32 + i * 16 + ml) * 32 + kg * 8];
            }
#pragma unroll
            for (int j = 0; j < 4; ++j)
                bf[j] = *(const frag8*)&Tb[hb][(j * 16 + ml) * 32 + kg * 8];
#pragma unroll
            for (int i = 0; i < 2; ++i)
#pragma unroll
                for (int j = 0; j < 4; ++j) {
                    acc[i][j] = __builtin_amdgcn_mfma_f32_16x16x32_bf16(af[i], bf[j], acc[i][j], 0, 0, 0);
                    acc[i][j] = __builtin_amdgcn_mfma_f32_16x16x32_bf16(lf[i], bf[j], acc[i][j], 0, 0, 0);
                }
        }
    }

#pragma unroll
    for (int i = 0; i < 2; ++i) {
        const int R0 = r0 + w * 32 + i * 16 + kg * 4;
#pragma unroll
        for (int j = 0; j < 4; ++j) {
            const int col = c0 + j * 16 + ml;
            const float bval = bo[col];
#pragma unroll
            for (int r = 0; r < 4; ++r)
                out[(size_t)(R0 + r) * 1024 + col] = acc[i][j][r] + bval;
        }
    }
}

// ---------------------------------------------------------------------------
extern "C" void kernel_launch(void* const* d_in, const int* in_sizes, int n_in,
                              void* d_out, int out_size, void* d_ws, size_t ws_size,
                              hipStream_t stream) {
    (void)in_sizes; (void)n_in; (void)out_size; (void)ws_size;
    const float* x  = (const float*)d_in[0];
    const float* Wq = (const float*)d_in[1];
    const float* bq = (const float*)d_in[2];
    const float* Wk = (const float*)d_in[3];
    const float* bk = (const float*)d_in[4];
    const float* Wv = (const float*)d_in[5];
    const float* bv = (const float*)d_in[6];
    const float* Wo = (const float*)d_in[7];
    const float* bo = (const float*)d_in[8];
    float* out = (float*)d_out;

    // Workspace plan (8MB units of NPER u16). High-water 65.3MB (< proven 67MB).
    //   [0-16MB)  xh,xl        -> dead after gemm_qkv -> Op0 (16.78MB, spills 0.78MB
    //                             into dead Wt rows [0,384))
    //   [16-24MB) Wt           (gemm_out only reads rows >=3072, offset >=22.29MB)
    //   [24-32MB) qh
    //   [32-48MB) khF,vhF      -> dead after attention -> cth,ctl
    //   [48-64.8MB) Op1        [64.8-65.3MB) lpart
    const size_t NPER = (size_t)BS * D;              // 4,194,304
    u16* base = (u16*)d_ws;
    u16* xh  = base;
    u16* xl  = base + NPER;
    u16* Wt  = base + 2 * NPER;
    u16* qh  = base + 3 * NPER;
    u16* khF = base + 4 * NPER;
    u16* vhF = base + 5 * NPER;
    float* Op0   = (float*)base;                     // overlays xh,xl (+0.78MB of Wt)
    float* Op1   = (float*)(base + 6 * NPER);
    float* lpart = (float*)(base + 6 * NPER) + NPER; // Op1 is NPER floats
    u16* cth = khF;                                  // overlays khF
    u16* ctl = vhF;                                  // overlays vhF

    convert_x  <<<dim3(BS * D / 1024), 256, 0, stream>>>(x, xh, xl);
    transpose_w<<<dim3(16, 64),        256, 0, stream>>>(Wq, Wk, Wv, Wo, Wt);
    gemm_qkv   <<<dim3(24, 32), 256, 0, stream>>>(Wt, xh, xl, bq, bk, bv,
                                                  qh, khF, vhF);
    attention_mfma<<<dim3(16, 32, 2), 512, 0, stream>>>(qh, khF, vhF, Op0, Op1, lpart);
    merge_ctx  <<<dim3(4096), 256, 0, stream>>>(Op0, Op1, lpart, cth, ctl);
    gemm_out   <<<dim3(32, 16), 256, 0, stream>>>(cth, ctl, Wt + (size_t)3072 * 1024,
                                                  bo, out);
}

// Round 8
// 446.664 us; speedup vs baseline: 2.1220x; 2.1220x over previous
//
#include <hip/hip_runtime.h>
#include <hip/hip_bf16.h>

// DPMultiHeadAttention MI355X — Round 8.
// R7 post-mortem: __launch_bounds__(512,6) capped VGPR at 85 -> compiler spilled the
// O-accumulators to scratch (VGPR_Count=40, WRITE_SIZE 1.84GB, FETCH 877MB, HBM-bound).
// R8: bounds -> (512,4) (cap 128; kernel needs ~100, R6 analog compiled at 64).
// Keeps R7 structure: Q hi-only QK, cross-block split-K x2 (grid 16x32x2), fp32
// O/l partials + streaming merge_ctx, single-buffer 32KB staging.

constexpr int B  = 2;
constexpr int S  = 2048;
constexpr int D  = 1024;
constexpr int H  = 16;
constexpr int DH = 64;
constexpr int BS = B * S;   // 4096

using u16 = unsigned short;
using u32 = unsigned int;
using frag8  = __attribute__((ext_vector_type(8)))  short;
using f32x4  = __attribute__((ext_vector_type(4)))  float;
using f32x16 = __attribute__((ext_vector_type(16))) float;

__device__ inline u16 f2bf(float x) {
    u32 u = __float_as_uint(x);
    return (u16)((u + 0x7FFF + ((u >> 16) & 1)) >> 16);
}
__device__ inline u32 pk2(float a, float b) {   // v_cvt_pk_bf16_f32
    __hip_bfloat162 t = __float22bfloat162_rn(make_float2(a, b));
    union { __hip_bfloat162 h; u32 u; } c; c.h = t; return c.u;
}
__device__ inline float unpk_lo(u32 p) { return __uint_as_float(p << 16); }
__device__ inline float unpk_hi(u32 p) { return __uint_as_float(p & 0xffff0000u); }

__device__ inline void glds16(const u16* g, const u16* l) {
    __builtin_amdgcn_global_load_lds(
        (const __attribute__((address_space(1))) void*)g,
        (__attribute__((address_space(3))) void*)l, 16, 0, 0);
}

// score scale: 1/sqrt(DH) * log2(e) (exp2-domain softmax), folded into K
#define KSC (0.125f * 1.44269504088896f)

// ---------------------------------------------------------------------------
// convert_x: x fp32 [4096][1024] -> xh, xl (split bf16)
// ---------------------------------------------------------------------------
__global__ __launch_bounds__(256) void convert_x(
    const float* __restrict__ x, u16* __restrict__ xh, u16* __restrict__ xl)
{
    const size_t idx = ((size_t)blockIdx.x * 256 + threadIdx.x) * 4;
    float4 v = *(const float4*)&x[idx];
    u32 h01 = pk2(v.x, v.y), h23 = pk2(v.z, v.w);
    *(uint2*)&xh[idx] = make_uint2(h01, h23);
    *(uint2*)&xl[idx] = make_uint2(pk2(v.x - unpk_lo(h01), v.y - unpk_hi(h01)),
                                   pk2(v.z - unpk_lo(h23), v.w - unpk_hi(h23)));
}

// ---------------------------------------------------------------------------
// transpose_w: Wt[4096][1024] bf16, k-contiguous rows.
// rows [0,3072): Wt[(t*16+h)*64+e][k] = W_t[h][k][e]; rows [3072,4096): Wo^T.
// ---------------------------------------------------------------------------
__global__ __launch_bounds__(256) void transpose_w(
    const float* __restrict__ Wq, const float* __restrict__ Wk,
    const float* __restrict__ Wv, const float* __restrict__ Wo,
    u16* __restrict__ Wt)
{
    const int kt = blockIdx.x;      // 0..15
    const int sl = blockIdx.y;      // 0..63
    const int tid = threadIdx.x;
    __shared__ float Ls[64][68];

    const float* src; int rstride;
    if (sl < 48) {
        const int t = sl >> 4, h = sl & 15;
        const float* Wp = (t == 0) ? Wq : ((t == 1) ? Wk : Wv);
        src = Wp + (size_t)h * D * DH;
        rstride = 64;
    } else {
        src = Wo + (sl - 48) * 64;
        rstride = 1024;
    }

    const int rr = tid >> 4, c4 = tid & 15;
#pragma unroll
    for (int p = 0; p < 4; ++p) {
        const int kk = p * 16 + rr;
        float4 v = *(const float4*)&src[(size_t)(kt * 64 + kk) * rstride + c4 * 4];
        *(float4*)&Ls[kk][c4 * 4] = v;
    }
    __syncthreads();
    const int rl = tid >> 2, ks = tid & 3;
    u16 ob[16];
#pragma unroll
    for (int i = 0; i < 16; ++i) ob[i] = f2bf(Ls[ks * 16 + i][rl]);
    u16* dst = Wt + (size_t)(sl * 64 + rl) * 1024 + kt * 64 + ks * 16;
    *(uint4*)&dst[0] = *(uint4*)&ob[0];
    *(uint4*)&dst[8] = *(uint4*)&ob[8];
}

// ---------------------------------------------------------------------------
// gemm_qkv: C[n][s] = sum_k Wt[n,k]*x[s,k]. A=Wt rounded, B=xh+xl split.
// 128x128 tile, 64 MFMA per barrier pair. grid (24,32).
// Epilogue: q -> qh row-major [bh][s][64] (hi only); k -> khF (scaled KSC);
//           v -> vhF. Fragment granule per (bh,kt): off = ((sub*4+ks)*64+lane)*8+j
// ---------------------------------------------------------------------------
__global__ __launch_bounds__(256, 3) void gemm_qkv(
    const u16* __restrict__ Wt, const u16* __restrict__ xh, const u16* __restrict__ xl,
    const float* __restrict__ bq, const float* __restrict__ bk, const float* __restrict__ bv,
    u16* __restrict__ qhO, u16* __restrict__ khF, u16* __restrict__ vhF)
{
    const int r0  = blockIdx.x * 128;     // n
    const int c0  = blockIdx.y * 128;     // s
    const int tid = threadIdx.x;
    const int w = tid >> 6, lane = tid & 63;
    const int wi = w >> 1, wj = w & 1;
    const int ml = lane & 15, kg = lane >> 4;

    __shared__ u16 Ta[2][128 * 32];
    __shared__ u16 Tb[2][128 * 32];
    __shared__ u16 Tl[2][128 * 32];

    const int srow = lane >> 2, sseg = lane & 3;
    const u16* Ag = Wt + (size_t)(r0 + w * 32 + srow) * 1024 + sseg * 8;
    const u16* Bg = xh + (size_t)(c0 + w * 32 + srow) * 1024 + sseg * 8;
    const u16* Lg = xl + (size_t)(c0 + w * 32 + srow) * 1024 + sseg * 8;

    f32x4 acc[4][4];
#pragma unroll
    for (int i = 0; i < 4; ++i)
#pragma unroll
        for (int j = 0; j < 4; ++j)
#pragma unroll
            for (int r = 0; r < 4; ++r) acc[i][j][r] = 0.f;

    for (int k0 = 0; k0 < 1024; k0 += 64) {
        __syncthreads();
#pragma unroll
        for (int hb = 0; hb < 2; ++hb) {
            const int ko = k0 + hb * 32;
            glds16(Ag + ko,             &Ta[hb][(w * 32) * 32]);
            glds16(Ag + 16 * 1024 + ko, &Ta[hb][(w * 32 + 16) * 32]);
            glds16(Bg + ko,             &Tb[hb][(w * 32) * 32]);
            glds16(Bg + 16 * 1024 + ko, &Tb[hb][(w * 32 + 16) * 32]);
            glds16(Lg + ko,             &Tl[hb][(w * 32) * 32]);
            glds16(Lg + 16 * 1024 + ko, &Tl[hb][(w * 32 + 16) * 32]);
        }
        __syncthreads();

#pragma unroll
        for (int hb = 0; hb < 2; ++hb) {
            frag8 af[4], bf[4], lf[4];
#pragma unroll
            for (int i = 0; i < 4; ++i)
                af[i] = *(const frag8*)&Ta[hb][(wi * 64 + i * 16 + ml) * 32 + kg * 8];
#pragma unroll
            for (int j = 0; j < 4; ++j) {
                bf[j] = *(const frag8*)&Tb[hb][(wj * 64 + j * 16 + ml) * 32 + kg * 8];
                lf[j] = *(const frag8*)&Tl[hb][(wj * 64 + j * 16 + ml) * 32 + kg * 8];
            }
#pragma unroll
            for (int i = 0; i < 4; ++i)
#pragma unroll
                for (int j = 0; j < 4; ++j) {
                    acc[i][j] = __builtin_amdgcn_mfma_f32_16x16x32_bf16(af[i], bf[j], acc[i][j], 0, 0, 0);
                    acc[i][j] = __builtin_amdgcn_mfma_f32_16x16x32_bf16(af[i], lf[j], acc[i][j], 0, 0, 0);
                }
        }
    }

    // epilogue: C/D col = ml (s), rows = n
    const int t = r0 >> 10;                      // 0:q 1:k 2:v
    if (t == 0) {
#pragma unroll
        for (int i = 0; i < 4; ++i) {
            const int Rb = r0 + wi * 64 + i * 16 + kg * 4;
            const int h  = (Rb >> 6) & 15;
            const int e0 = Rb & 63;
            float bv4[4];
#pragma unroll
            for (int r = 0; r < 4; ++r) bv4[r] = bq[(Rb & 1023) + r];
#pragma unroll
            for (int j = 0; j < 4; ++j) {
                const int s  = c0 + wj * 64 + j * 16 + ml;
                const int bb = s >> 11, sl = s & (S - 1);
                float v[4];
#pragma unroll
                for (int r = 0; r < 4; ++r) v[r] = acc[i][j][r] + bv4[r];
                const size_t base = ((size_t)(bb * H + h) * S + sl) * 64 + e0;
                *(uint2*)&qhO[base] = make_uint2(pk2(v[0], v[1]), pk2(v[2], v[3]));
            }
        }
    } else if (t == 1) {
#pragma unroll
        for (int i = 0; i < 4; ++i) {
            const int Rb = r0 + wi * 64 + i * 16 + kg * 4;
            const int h  = (Rb >> 6) & 15;
            const int e0 = Rb & 63;
            const int ksf = e0 >> 4, Hf = (e0 >> 3) & 1, j0 = e0 & 7;
            float bv4[4];
#pragma unroll
            for (int r = 0; r < 4; ++r) bv4[r] = bk[(Rb & 1023) + r];
#pragma unroll
            for (int j = 0; j < 4; ++j) {
                const int s  = c0 + wj * 64 + j * 16 + ml;
                const int bb = s >> 11, sl = s & (S - 1);
                const int bh = bb * H + h;
                const int kt = sl >> 6, sub = (sl >> 5) & 1, klow = sl & 31;
                const int lanef = klow | (Hf << 5);
                const size_t off = (size_t)bh * 131072 +
                    (size_t)(((kt * 2 + sub) * 4 + ksf) * 64 + lanef) * 8 + j0;
                float v[4];
#pragma unroll
                for (int r = 0; r < 4; ++r) v[r] = (acc[i][j][r] + bv4[r]) * KSC;
                *(uint2*)&khF[off] = make_uint2(pk2(v[0], v[1]), pk2(v[2], v[3]));
            }
        }
    } else {
#pragma unroll
        for (int i = 0; i < 4; ++i) {
            const int Rb  = r0 + wi * 64 + i * 16 + kg * 4;
            const int h   = (Rb >> 6) & 15;
            const int dh0 = Rb & 63;
            float bv4[4];
#pragma unroll
            for (int r = 0; r < 4; ++r) bv4[r] = bv[(Rb & 1023) + r];
#pragma unroll
            for (int j = 0; j < 4; ++j) {
                const int s  = c0 + wj * 64 + j * 16 + ml;
                const int bb = s >> 11, sl = s & (S - 1);
                const int bh = bb * H + h;
                const int kt = sl >> 6, key = sl & 63;
                const int ksf = key >> 4, Hf = (key >> 3) & 1, j0 = key & 7;
                const size_t tb = (size_t)bh * 131072 + (size_t)j0 +
                                  (size_t)((kt * 2) * 4 + ksf) * 512;
#pragma unroll
                for (int r = 0; r < 4; ++r) {
                    const int dh = dh0 + r;
                    const int sub = dh >> 5;
                    const int lanef = (dh & 31) | (Hf << 5);
                    vhF[tb + (size_t)sub * 2048 + (size_t)lanef * 8] =
                        f2bf(acc[i][j][r] + bv4[r]);
                }
            }
        }
    }
}

// ---------------------------------------------------------------------------
// attention: split-K x2 across blocks + x2 in-block. grid (16, 32, 2).
// Block: 512 thr = 2 groups x 4 waves; part p group g handles keys
// [(p*2+g)*512, +512) for the same 128 q rows (8 iters of 64 keys).
// No-max exp2 softmax; Q hi-only (8 QK MFMA/iter). Writes UNNORMALIZED fp32
// O-partial [p][bh][s][64] + l-partial [p][bh][s]; merge_ctx combines.
// bounds (512,4): VGPR cap 128 — accumulators (~100 live) MUST NOT spill (R7 lesson).
// ---------------------------------------------------------------------------
__global__ __launch_bounds__(512, 4) void attention_mfma(
    const u16* __restrict__ qh, const u16* __restrict__ khF,
    const u16* __restrict__ vhF,
    float* __restrict__ Op0, float* __restrict__ Op1,
    float* __restrict__ lpart)
{
    const int qt  = blockIdx.x;      // 0..15
    const int bh  = blockIdx.y;      // 0..31
    const int p   = blockIdx.z;      // 0..1
    const int tid = threadIdx.x;
    const int w   = tid >> 6, wl = w & 3, g = w >> 2;
    const int lane = tid & 63;
    const int nq  = lane & 31;
    const int Hh  = lane >> 5;

    __shared__ union {
        u16   stg[2][2][4096];   // [group][K,V][64keys x 64dh] = 32KB single buf
        float xch[128][72];      // merge/output buffer 36.9KB
    } L;
    __shared__ float lsum[2][128];

    // Q fragments hi (B-operand), register resident: dh = ks*16 + Hh*8 + j
    const int qrow = qt * 128 + wl * 32 + nq;
    const u16* qhp = qh + ((size_t)bh * S + qrow) * DH;
    frag8 qf[4];
#pragma unroll
    for (int ks = 0; ks < 4; ++ks) qf[ks] = *(const frag8*)(qhp + ks * 16 + Hh * 8);

    f32x16 O0, O1;
#pragma unroll
    for (int i = 0; i < 16; ++i) { O0[i] = 0.f; O1[i] = 0.f; }
    float l_run = 0.f;

    const int go = wl * 1024 + lane * 8;
    const size_t bhb = (size_t)bh * 131072;
    u16* sK = &L.stg[g][0][0];
    u16* sV = &L.stg[g][1][0];

    for (int it = 0; it < 8; ++it) {
        const size_t kb = bhb + (size_t)((p * 2 + g) * 8 + it) * 4096;
        __syncthreads();                 // prior reads of stg done
        glds16(khF + kb + go,       sK + wl * 1024);
        glds16(khF + kb + go + 512, sK + wl * 1024 + 512);
        glds16(vhF + kb + go,       sV + wl * 1024);
        glds16(vhF + kb + go + 512, sV + wl * 1024 + 512);
        __syncthreads();                 // loads complete (vmcnt drain)

        // ---- S^T = K·Q^T  (K rounded+scaled; Q hi only)
        f32x16 sa0, sa1;
#pragma unroll
        for (int i = 0; i < 16; ++i) { sa0[i] = 0.f; sa1[i] = 0.f; }
#pragma unroll
        for (int ks = 0; ks < 4; ++ks) {
            frag8 k0 = *(const frag8*)&sK[(ks * 64 + lane) * 8];
            frag8 k1 = *(const frag8*)&sK[((4 + ks) * 64 + lane) * 8];
            sa0 = __builtin_amdgcn_mfma_f32_32x32x16_bf16(k0, qf[ks], sa0, 0, 0, 0);
            sa1 = __builtin_amdgcn_mfma_f32_32x32x16_bf16(k1, qf[ks], sa1, 0, 0, 0);
        }

        // ---- no-max softmax numerators
        float psum = 0.f;
        u32 ph0[8], ph1[8];
#pragma unroll
        for (int u = 0; u < 8; ++u) {
            float e0 = exp2f(sa0[2 * u]);
            float e1 = exp2f(sa0[2 * u + 1]);
            float f0 = exp2f(sa1[2 * u]);
            float f1 = exp2f(sa1[2 * u + 1]);
            psum += (e0 + e1) + (f0 + f1);
            ph0[u] = pk2(e0, e1);
            ph1[u] = pk2(f0, f1);
        }
        l_run += psum;

        // ---- O^T += V^T · P^T  (P^T B-frags via half-swap shuffles)
#pragma unroll
        for (int ks = 0; ks < 4; ++ks) {
            const u32* PH = (ks < 2) ? ph0 : ph1;
            const int ks2 = ks & 1;
            const int oi = 4 * ks2 + 2 * Hh;
            const int si = 4 * ks2 + 2 * (1 - Hh);
            u32 rh0 = __shfl_xor(PH[si], 32), rh1 = __shfl_xor(PH[si + 1], 32);
            union { u32 u[4]; frag8 f; } fh;
            if (Hh == 0) {
                fh.u[0] = PH[oi]; fh.u[1] = PH[oi + 1]; fh.u[2] = rh0; fh.u[3] = rh1;
            } else {
                fh.u[0] = rh0; fh.u[1] = rh1; fh.u[2] = PH[oi]; fh.u[3] = PH[oi + 1];
            }
            frag8 v0 = *(const frag8*)&sV[(ks * 64 + lane) * 8];
            frag8 v1 = *(const frag8*)&sV[((4 + ks) * 64 + lane) * 8];
            O0 = __builtin_amdgcn_mfma_f32_32x32x16_bf16(v0, fh.f, O0, 0, 0, 0);
            O1 = __builtin_amdgcn_mfma_f32_32x32x16_bf16(v1, fh.f, O1, 0, 0, 0);
        }
    }

    // ---- combine the two in-block groups (pure sums), write fp32 partial
    l_run += __shfl_xor(l_run, 32);
    const int qr = wl * 32 + nq;
    if (Hh == 0) lsum[g][qr] = l_run;
    __syncthreads();                     // stg reads done; union reuse safe

    if (g == 1) {
#pragma unroll
        for (int cdh = 0; cdh < 2; ++cdh)
#pragma unroll
            for (int rg = 0; rg < 4; ++rg) {
                const f32x16& O = cdh ? O1 : O0;
                float4 v4;
                v4.x = O[4 * rg + 0]; v4.y = O[4 * rg + 1];
                v4.z = O[4 * rg + 2]; v4.w = O[4 * rg + 3];
                *(float4*)&L.xch[qr][cdh * 32 + rg * 8 + Hh * 4] = v4;
            }
    }
    __syncthreads();
    if (g == 0) {
#pragma unroll
        for (int cdh = 0; cdh < 2; ++cdh)
#pragma unroll
            for (int rg = 0; rg < 4; ++rg) {
                float4 p4 = *(const float4*)&L.xch[qr][cdh * 32 + rg * 8 + Hh * 4];
                const f32x16& O = cdh ? O1 : O0;
                float4 v4;
                v4.x = O[4 * rg + 0] + p4.x;
                v4.y = O[4 * rg + 1] + p4.y;
                v4.z = O[4 * rg + 2] + p4.z;
                v4.w = O[4 * rg + 3] + p4.w;
                *(float4*)&L.xch[qr][cdh * 32 + rg * 8 + Hh * 4] = v4;
            }
    }
    __syncthreads();

    float* Op = p ? Op1 : Op0;
#pragma unroll
    for (int pass = 0; pass < 4; ++pass) {
        const int chunk = pass * 512 + tid;          // 0..2047
        const int qi = chunk >> 4, seg = chunk & 15;
        float4 v4 = *(const float4*)&L.xch[qi][seg * 4];
        *(float4*)&Op[((size_t)bh * S + qt * 128 + qi) * 64 + seg * 4] = v4;
    }
    if (tid < 128)
        lpart[((size_t)p * 32 + bh) * S + qt * 128 + tid] = lsum[0][tid] + lsum[1][tid];
}

// ---------------------------------------------------------------------------
// merge_ctx: ctx = (Op0 + Op1) / (l0 + l1), split-bf16 out. Streaming.
// idx over [bh][s][c4]: 32*2048*16 = 1,048,576 threads. grid 4096.
// ---------------------------------------------------------------------------
__global__ __launch_bounds__(256) void merge_ctx(
    const float* __restrict__ Op0, const float* __restrict__ Op1,
    const float* __restrict__ lp, u16* __restrict__ cth, u16* __restrict__ ctl)
{
    const int idx = blockIdx.x * 256 + threadIdx.x;
    const int bh = idx >> 15;
    const int r  = idx & 32767;
    const int s  = r >> 4, c4 = r & 15;
    const size_t ob = ((size_t)bh * S + s) * 64 + c4 * 4;
    float4 p0 = *(const float4*)&Op0[ob];
    float4 p1 = *(const float4*)&Op1[ob];
    const float inv = 1.f / (lp[(size_t)bh * S + s] + lp[(size_t)(32 + bh) * S + s]);
    float v0 = (p0.x + p1.x) * inv, v1 = (p0.y + p1.y) * inv;
    float v2 = (p0.z + p1.z) * inv, v3 = (p0.w + p1.w) * inv;
    u32 h01 = pk2(v0, v1), h23 = pk2(v2, v3);
    const int b = bh >> 4, h = bh & 15;
    const size_t base = ((size_t)(b * S + s)) * D + h * 64 + c4 * 4;
    *(uint2*)&cth[base] = make_uint2(h01, h23);
    *(uint2*)&ctl[base] = make_uint2(pk2(v0 - unpk_lo(h01), v1 - unpk_hi(h01)),
                                     pk2(v2 - unpk_lo(h23), v3 - unpk_hi(h23)));
}

// ---------------------------------------------------------------------------
// gemm_out: out[s][d] = sum_k ctx[s,k]*Wo[k,d] + bo. A=cth+ctl split, B=Wt+3072.
// 128x64 tile, grid (32,16).
// ---------------------------------------------------------------------------
__global__ __launch_bounds__(256, 4) void gemm_out(
    const u16* __restrict__ Ah, const u16* __restrict__ Al,
    const u16* __restrict__ Bh, const float* __restrict__ bo,
    float* __restrict__ out)
{
    const int r0  = blockIdx.x * 128;     // s
    const int c0  = blockIdx.y * 64;      // d
    const int tid = threadIdx.x;
    const int w = tid >> 6, lane = tid & 63;
    const int ml = lane & 15, kg = lane >> 4;

    __shared__ u16 Ta[2][128 * 32];
    __shared__ u16 Tl[2][128 * 32];
    __shared__ u16 Tb[2][64 * 32];

    const int srow = lane >> 2, sseg = lane & 3;
    const u16* Ag = Ah + (size_t)(r0 + w * 32 + srow) * 1024 + sseg * 8;
    const u16* Lg = Al + (size_t)(r0 + w * 32 + srow) * 1024 + sseg * 8;
    const u16* Bg = Bh + (size_t)(c0 + w * 16 + srow) * 1024 + sseg * 8;

    f32x4 acc[2][4];
#pragma unroll
    for (int i = 0; i < 2; ++i)
#pragma unroll
        for (int j = 0; j < 4; ++j)
#pragma unroll
            for (int r = 0; r < 4; ++r) acc[i][j][r] = 0.f;

    for (int k0 = 0; k0 < 1024; k0 += 64) {
        __syncthreads();
#pragma unroll
        for (int hb = 0; hb < 2; ++hb) {
            const int ko = k0 + hb * 32;
            glds16(Ag + ko,             &Ta[hb][(w * 32) * 32]);
            glds16(Ag + 16 * 1024 + ko, &Ta[hb][(w * 32 + 16) * 32]);
            glds16(Lg + ko,             &Tl[hb][(w * 32) * 32]);
            glds16(Lg + 16 * 1024 + ko, &Tl[hb][(w * 32 + 16) * 32]);
            glds16(Bg + ko,             &Tb[hb][(w * 16) * 32]);
        }
        __syncthreads();

#pragma unroll
        for (int hb = 0; hb < 2; ++hb) {
            frag8 af[2], lf[2], bf[4];
#pragma unroll
            for (int i = 0; i < 2; ++i) {
                af[i] = *(const frag8*)&Ta[hb][(w * 32 + i * 16 + ml) * 32 + kg * 8];
                lf[i] = *(const frag8*)&Tl[hb][(w * 32 + i * 16 + ml) * 32 + kg * 8];
            }
#pragma unroll
            for (int j = 0; j < 4; ++j)
                bf[j] = *(const frag8*)&Tb[hb][(j * 16 + ml) * 32 + kg * 8];
#pragma unroll
            for (int i = 0; i < 2; ++i)
#pragma unroll
                for (int j = 0; j < 4; ++j) {
                    acc[i][j] = __builtin_amdgcn_mfma_f32_16x16x32_bf16(af[i], bf[j], acc[i][j], 0, 0, 0);
                    acc[i][j] = __builtin_amdgcn_mfma_f32_16x16x32_bf16(lf[i], bf[j], acc[i][j], 0, 0, 0);
                }
        }
    }

#pragma unroll
    for (int i = 0; i < 2; ++i) {
        const int R0 = r0 + w * 32 + i * 16 + kg * 4;
#pragma unroll
        for (int j = 0; j < 4; ++j) {
            const int col = c0 + j * 16 + ml;
            const float bval = bo[col];
#pragma unroll
            for (int r = 0; r < 4; ++r)
                out[(size_t)(R0 + r) * 1024 + col] = acc[i][j][r] + bval;
        }
    }
}

// ---------------------------------------------------------------------------
extern "C" void kernel_launch(void* const* d_in, const int* in_sizes, int n_in,
                              void* d_out, int out_size, void* d_ws, size_t ws_size,
                              hipStream_t stream) {
    (void)in_sizes; (void)n_in; (void)out_size; (void)ws_size;
    const float* x  = (const float*)d_in[0];
    const float* Wq = (const float*)d_in[1];
    const float* bq = (const float*)d_in[2];
    const float* Wk = (const float*)d_in[3];
    const float* bk = (const float*)d_in[4];
    const float* Wv = (const float*)d_in[5];
    const float* bv = (const float*)d_in[6];
    const float* Wo = (const float*)d_in[7];
    const float* bo = (const float*)d_in[8];
    float* out = (float*)d_out;

    // Workspace plan (NPER u16 = 8MB units). High-water 65.3MB (< proven 67MB).
    //   [0-16MB)  xh,xl      -> dead after gemm_qkv -> Op0 (16.78MB; 0.78MB spills
    //                           into dead Wt rows [0,384))
    //   [16-24MB) Wt         (gemm_out only reads rows >=3072)
    //   [24-32MB) qh
    //   [32-48MB) khF,vhF    -> dead after attention -> cth,ctl
    //   [48-64.8MB) Op1      [64.8-65.3MB) lpart
    const size_t NPER = (size_t)BS * D;              // 4,194,304
    u16* base = (u16*)d_ws;
    u16* xh  = base;
    u16* xl  = base + NPER;
    u16* Wt  = base + 2 * NPER;
    u16* qh  = base + 3 * NPER;
    u16* khF = base + 4 * NPER;
    u16* vhF = base + 5 * NPER;
    float* Op0   = (float*)base;                     // overlays xh,xl
    float* Op1   = (float*)(base + 6 * NPER);
    float* lpart = (float*)(base + 6 * NPER) + NPER; // Op1 is NPER floats
    u16* cth = khF;                                  // overlays khF
    u16* ctl = vhF;                                  // overlays vhF

    convert_x  <<<dim3(BS * D / 1024), 256, 0, stream>>>(x, xh, xl);
    transpose_w<<<dim3(16, 64),        256, 0, stream>>>(Wq, Wk, Wv, Wo, Wt);
    gemm_qkv   <<<dim3(24, 32), 256, 0, stream>>>(Wt, xh, xl, bq, bk, bv,
                                                  qh, khF, vhF);
    attention_mfma<<<dim3(16, 32, 2), 512, 0, stream>>>(qh, khF, vhF, Op0, Op1, lpart);
    merge_ctx  <<<dim3(4096), 256, 0, stream>>>(Op0, Op1, lpart, cth, ctl);
    gemm_out   <<<dim3(32, 16), 256, 0, stream>>>(cth, ctl, Wt + (size_t)3072 * 1024,
                                                  bo, out);
}

// Round 9
// 273.141 us; speedup vs baseline: 3.4701x; 1.6353x over previous
//
#include <hip/hip_runtime.h>
#include <hip/hip_bf16.h>

// DPMultiHeadAttention MI355X — Round 9.
// R8 post-mortem: cross-block split-K caused 762MB HBM traffic (no L2 reuse across
// scattered qt-blocks + register-cap scratch). R9 reverts to R6's clean in-block
// structure (124us, VGPR 64, no excess traffic) and keeps R7/R8's accuracy-proven
// Q-hi-only QK (8 MFMA/iter) + no-max exp2 softmax. NEW: XCD-aware swizzle — all 16
// qt-blocks of a bh share id%8 -> same XCD -> K/V (512KB/head) L2-resident.

constexpr int B  = 2;
constexpr int S  = 2048;
constexpr int D  = 1024;
constexpr int H  = 16;
constexpr int DH = 64;
constexpr int BS = B * S;   // 4096

using u16 = unsigned short;
using u32 = unsigned int;
using frag8  = __attribute__((ext_vector_type(8)))  short;
using f32x4  = __attribute__((ext_vector_type(4)))  float;
using f32x16 = __attribute__((ext_vector_type(16))) float;

__device__ inline u16 f2bf(float x) {
    u32 u = __float_as_uint(x);
    return (u16)((u + 0x7FFF + ((u >> 16) & 1)) >> 16);
}
__device__ inline u32 pk2(float a, float b) {   // v_cvt_pk_bf16_f32
    __hip_bfloat162 t = __float22bfloat162_rn(make_float2(a, b));
    union { __hip_bfloat162 h; u32 u; } c; c.h = t; return c.u;
}
__device__ inline float unpk_lo(u32 p) { return __uint_as_float(p << 16); }
__device__ inline float unpk_hi(u32 p) { return __uint_as_float(p & 0xffff0000u); }

__device__ inline void glds16(const u16* g, const u16* l) {
    __builtin_amdgcn_global_load_lds(
        (const __attribute__((address_space(1))) void*)g,
        (__attribute__((address_space(3))) void*)l, 16, 0, 0);
}

// score scale: 1/sqrt(DH) * log2(e) (exp2-domain softmax), folded into K
#define KSC (0.125f * 1.44269504088896f)

// ---------------------------------------------------------------------------
// convert_x: x fp32 [4096][1024] -> xh, xl (split bf16)
// ---------------------------------------------------------------------------
__global__ __launch_bounds__(256) void convert_x(
    const float* __restrict__ x, u16* __restrict__ xh, u16* __restrict__ xl)
{
    const size_t idx = ((size_t)blockIdx.x * 256 + threadIdx.x) * 4;
    float4 v = *(const float4*)&x[idx];
    u32 h01 = pk2(v.x, v.y), h23 = pk2(v.z, v.w);
    *(uint2*)&xh[idx] = make_uint2(h01, h23);
    *(uint2*)&xl[idx] = make_uint2(pk2(v.x - unpk_lo(h01), v.y - unpk_hi(h01)),
                                   pk2(v.z - unpk_lo(h23), v.w - unpk_hi(h23)));
}

// ---------------------------------------------------------------------------
// transpose_w: Wt[4096][1024] bf16, k-contiguous rows.
// rows [0,3072): Wt[(t*16+h)*64+e][k] = W_t[h][k][e]; rows [3072,4096): Wo^T.
// ---------------------------------------------------------------------------
__global__ __launch_bounds__(256) void transpose_w(
    const float* __restrict__ Wq, const float* __restrict__ Wk,
    const float* __restrict__ Wv, const float* __restrict__ Wo,
    u16* __restrict__ Wt)
{
    const int kt = blockIdx.x;      // 0..15
    const int sl = blockIdx.y;      // 0..63
    const int tid = threadIdx.x;
    __shared__ float Ls[64][68];

    const float* src; int rstride;
    if (sl < 48) {
        const int t = sl >> 4, h = sl & 15;
        const float* Wp = (t == 0) ? Wq : ((t == 1) ? Wk : Wv);
        src = Wp + (size_t)h * D * DH;
        rstride = 64;
    } else {
        src = Wo + (sl - 48) * 64;
        rstride = 1024;
    }

    const int rr = tid >> 4, c4 = tid & 15;
#pragma unroll
    for (int p = 0; p < 4; ++p) {
        const int kk = p * 16 + rr;
        float4 v = *(const float4*)&src[(size_t)(kt * 64 + kk) * rstride + c4 * 4];
        *(float4*)&Ls[kk][c4 * 4] = v;
    }
    __syncthreads();
    const int rl = tid >> 2, ks = tid & 3;
    u16 ob[16];
#pragma unroll
    for (int i = 0; i < 16; ++i) ob[i] = f2bf(Ls[ks * 16 + i][rl]);
    u16* dst = Wt + (size_t)(sl * 64 + rl) * 1024 + kt * 64 + ks * 16;
    *(uint4*)&dst[0] = *(uint4*)&ob[0];
    *(uint4*)&dst[8] = *(uint4*)&ob[8];
}

// ---------------------------------------------------------------------------
// gemm_qkv: C[n][s] = sum_k Wt[n,k]*x[s,k]. A=Wt rounded, B=xh+xl split.
// 128x128 tile, 64 MFMA per barrier pair. grid (24,32).
// Epilogue: q -> qh row-major [bh][s][64] (hi only); k -> khF (scaled KSC);
//           v -> vhF. Fragment granule per (bh,kt): off = ((sub*4+ks)*64+lane)*8+j
// ---------------------------------------------------------------------------
__global__ __launch_bounds__(256, 3) void gemm_qkv(
    const u16* __restrict__ Wt, const u16* __restrict__ xh, const u16* __restrict__ xl,
    const float* __restrict__ bq, const float* __restrict__ bk, const float* __restrict__ bv,
    u16* __restrict__ qhO, u16* __restrict__ khF, u16* __restrict__ vhF)
{
    const int r0  = blockIdx.x * 128;     // n
    const int c0  = blockIdx.y * 128;     // s
    const int tid = threadIdx.x;
    const int w = tid >> 6, lane = tid & 63;
    const int wi = w >> 1, wj = w & 1;
    const int ml = lane & 15, kg = lane >> 4;

    __shared__ u16 Ta[2][128 * 32];
    __shared__ u16 Tb[2][128 * 32];
    __shared__ u16 Tl[2][128 * 32];

    const int srow = lane >> 2, sseg = lane & 3;
    const u16* Ag = Wt + (size_t)(r0 + w * 32 + srow) * 1024 + sseg * 8;
    const u16* Bg = xh + (size_t)(c0 + w * 32 + srow) * 1024 + sseg * 8;
    const u16* Lg = xl + (size_t)(c0 + w * 32 + srow) * 1024 + sseg * 8;

    f32x4 acc[4][4];
#pragma unroll
    for (int i = 0; i < 4; ++i)
#pragma unroll
        for (int j = 0; j < 4; ++j)
#pragma unroll
            for (int r = 0; r < 4; ++r) acc[i][j][r] = 0.f;

    for (int k0 = 0; k0 < 1024; k0 += 64) {
        __syncthreads();
#pragma unroll
        for (int hb = 0; hb < 2; ++hb) {
            const int ko = k0 + hb * 32;
            glds16(Ag + ko,             &Ta[hb][(w * 32) * 32]);
            glds16(Ag + 16 * 1024 + ko, &Ta[hb][(w * 32 + 16) * 32]);
            glds16(Bg + ko,             &Tb[hb][(w * 32) * 32]);
            glds16(Bg + 16 * 1024 + ko, &Tb[hb][(w * 32 + 16) * 32]);
            glds16(Lg + ko,             &Tl[hb][(w * 32) * 32]);
            glds16(Lg + 16 * 1024 + ko, &Tl[hb][(w * 32 + 16) * 32]);
        }
        __syncthreads();

#pragma unroll
        for (int hb = 0; hb < 2; ++hb) {
            frag8 af[4], bf[4], lf[4];
#pragma unroll
            for (int i = 0; i < 4; ++i)
                af[i] = *(const frag8*)&Ta[hb][(wi * 64 + i * 16 + ml) * 32 + kg * 8];
#pragma unroll
            for (int j = 0; j < 4; ++j) {
                bf[j] = *(const frag8*)&Tb[hb][(wj * 64 + j * 16 + ml) * 32 + kg * 8];
                lf[j] = *(const frag8*)&Tl[hb][(wj * 64 + j * 16 + ml) * 32 + kg * 8];
            }
#pragma unroll
            for (int i = 0; i < 4; ++i)
#pragma unroll
                for (int j = 0; j < 4; ++j) {
                    acc[i][j] = __builtin_amdgcn_mfma_f32_16x16x32_bf16(af[i], bf[j], acc[i][j], 0, 0, 0);
                    acc[i][j] = __builtin_amdgcn_mfma_f32_16x16x32_bf16(af[i], lf[j], acc[i][j], 0, 0, 0);
                }
        }
    }

    // epilogue: C/D col = ml (s), rows = n
    const int t = r0 >> 10;                      // 0:q 1:k 2:v
    if (t == 0) {
#pragma unroll
        for (int i = 0; i < 4; ++i) {
            const int Rb = r0 + wi * 64 + i * 16 + kg * 4;
            const int h  = (Rb >> 6) & 15;
            const int e0 = Rb & 63;
            float bv4[4];
#pragma unroll
            for (int r = 0; r < 4; ++r) bv4[r] = bq[(Rb & 1023) + r];
#pragma unroll
            for (int j = 0; j < 4; ++j) {
                const int s  = c0 + wj * 64 + j * 16 + ml;
                const int bb = s >> 11, sl = s & (S - 1);
                float v[4];
#pragma unroll
                for (int r = 0; r < 4; ++r) v[r] = acc[i][j][r] + bv4[r];
                const size_t base = ((size_t)(bb * H + h) * S + sl) * 64 + e0;
                *(uint2*)&qhO[base] = make_uint2(pk2(v[0], v[1]), pk2(v[2], v[3]));
            }
        }
    } else if (t == 1) {
#pragma unroll
        for (int i = 0; i < 4; ++i) {
            const int Rb = r0 + wi * 64 + i * 16 + kg * 4;
            const int h  = (Rb >> 6) & 15;
            const int e0 = Rb & 63;
            const int ksf = e0 >> 4, Hf = (e0 >> 3) & 1, j0 = e0 & 7;
            float bv4[4];
#pragma unroll
            for (int r = 0; r < 4; ++r) bv4[r] = bk[(Rb & 1023) + r];
#pragma unroll
            for (int j = 0; j < 4; ++j) {
                const int s  = c0 + wj * 64 + j * 16 + ml;
                const int bb = s >> 11, sl = s & (S - 1);
                const int bh = bb * H + h;
                const int kt = sl >> 6, sub = (sl >> 5) & 1, klow = sl & 31;
                const int lanef = klow | (Hf << 5);
                const size_t off = (size_t)bh * 131072 +
                    (size_t)(((kt * 2 + sub) * 4 + ksf) * 64 + lanef) * 8 + j0;
                float v[4];
#pragma unroll
                for (int r = 0; r < 4; ++r) v[r] = (acc[i][j][r] + bv4[r]) * KSC;
                *(uint2*)&khF[off] = make_uint2(pk2(v[0], v[1]), pk2(v[2], v[3]));
            }
        }
    } else {
#pragma unroll
        for (int i = 0; i < 4; ++i) {
            const int Rb  = r0 + wi * 64 + i * 16 + kg * 4;
            const int h   = (Rb >> 6) & 15;
            const int dh0 = Rb & 63;
            float bv4[4];
#pragma unroll
            for (int r = 0; r < 4; ++r) bv4[r] = bv[(Rb & 1023) + r];
#pragma unroll
            for (int j = 0; j < 4; ++j) {
                const int s  = c0 + wj * 64 + j * 16 + ml;
                const int bb = s >> 11, sl = s & (S - 1);
                const int bh = bb * H + h;
                const int kt = sl >> 6, key = sl & 63;
                const int ksf = key >> 4, Hf = (key >> 3) & 1, j0 = key & 7;
                const size_t tb = (size_t)bh * 131072 + (size_t)j0 +
                                  (size_t)((kt * 2) * 4 + ksf) * 512;
#pragma unroll
                for (int r = 0; r < 4; ++r) {
                    const int dh = dh0 + r;
                    const int sub = dh >> 5;
                    const int lanef = (dh & 31) | (Hf << 5);
                    vhF[tb + (size_t)sub * 2048 + (size_t)lanef * 8] =
                        f2bf(acc[i][j][r] + bv4[r]);
                }
            }
        }
    }
}

// ---------------------------------------------------------------------------
// attention: R6 structure + Q-hi-only + XCD swizzle. 1D grid 512, 512 thr
// (2 key-groups x 4 waves). Decode: bh = (id&7) | (((id>>3)&3)<<3), qt = id>>5
// -> all 16 qt-blocks of a bh share id%8 (same XCD; K/V L2-resident).
// Group g handles keys [g*1024,(g+1)*1024) for the same 128 q rows.
// Double-buffered prefetch, ONE barrier/iter. No-max exp2 softmax (l deferred).
// Direct split-bf16 ctx output; in-block merge only.
// ---------------------------------------------------------------------------
__global__ __launch_bounds__(512, 4) void attention_mfma(
    const u16* __restrict__ qh, const u16* __restrict__ khF,
    const u16* __restrict__ vhF,
    u16* __restrict__ cth, u16* __restrict__ ctl)
{
    const int id  = blockIdx.x;
    const int bh  = (id & 7) | (((id >> 3) & 3) << 3);   // 0..31
    const int qt  = id >> 5;                              // 0..15
    const int b   = bh >> 4, h = bh & 15;
    const int tid = threadIdx.x;
    const int w   = tid >> 6, wl = w & 3, g = w >> 2;
    const int lane = tid & 63;
    const int nq  = lane & 31;
    const int Hh  = lane >> 5;

    __shared__ union {
        u16   stg[2][2][2][4096];   // [group][buf][K,V][64keys x 64dh] = 64KB
        float xch[128][72];         // merge/output buffer 36.9KB
    } L;
    __shared__ float lsum[2][128];

    // Q fragments hi (B-operand), register resident: dh = ks*16 + Hh*8 + j
    const int qrow = qt * 128 + wl * 32 + nq;
    const u16* qhp = qh + ((size_t)bh * S + qrow) * DH;
    frag8 qf[4];
#pragma unroll
    for (int ks = 0; ks < 4; ++ks) qf[ks] = *(const frag8*)(qhp + ks * 16 + Hh * 8);

    f32x16 O0, O1;
#pragma unroll
    for (int i = 0; i < 16; ++i) { O0[i] = 0.f; O1[i] = 0.f; }
    float l_run = 0.f;

    const int go = wl * 1024 + lane * 8;
    const size_t bhb = (size_t)bh * 131072;

    // prefetch tile 0 into buf 0
    {
        const size_t kb = bhb + (size_t)(g * 16) * 4096;
        glds16(khF + kb + go,       &L.stg[g][0][0][wl * 1024]);
        glds16(khF + kb + go + 512, &L.stg[g][0][0][wl * 1024 + 512]);
        glds16(vhF + kb + go,       &L.stg[g][0][1][wl * 1024]);
        glds16(vhF + kb + go + 512, &L.stg[g][0][1][wl * 1024 + 512]);
    }

    for (int it = 0; it < 16; ++it) {
        __syncthreads();   // buf[it&1] loads drained; prev reads of buf[(it+1)&1] done
        if (it < 15) {     // prefetch next tile into the other buffer
            const size_t kb = bhb + (size_t)(g * 16 + it + 1) * 4096;
            const int nb = (it + 1) & 1;
            glds16(khF + kb + go,       &L.stg[g][nb][0][wl * 1024]);
            glds16(khF + kb + go + 512, &L.stg[g][nb][0][wl * 1024 + 512]);
            glds16(vhF + kb + go,       &L.stg[g][nb][1][wl * 1024]);
            glds16(vhF + kb + go + 512, &L.stg[g][nb][1][wl * 1024 + 512]);
        }
        const u16* sK = &L.stg[g][it & 1][0][0];
        const u16* sV = &L.stg[g][it & 1][1][0];

        // ---- S^T = K·Q^T  (K rounded+scaled; Q hi only)
        f32x16 sa0, sa1;
#pragma unroll
        for (int i = 0; i < 16; ++i) { sa0[i] = 0.f; sa1[i] = 0.f; }
#pragma unroll
        for (int ks = 0; ks < 4; ++ks) {
            frag8 k0 = *(const frag8*)&sK[(ks * 64 + lane) * 8];
            frag8 k1 = *(const frag8*)&sK[((4 + ks) * 64 + lane) * 8];
            sa0 = __builtin_amdgcn_mfma_f32_32x32x16_bf16(k0, qf[ks], sa0, 0, 0, 0);
            sa1 = __builtin_amdgcn_mfma_f32_32x32x16_bf16(k1, qf[ks], sa1, 0, 0, 0);
        }

        // ---- no-max softmax numerators; l accumulated per-lane (merge deferred)
        float psum = 0.f;
        u32 ph0[8], ph1[8];
#pragma unroll
        for (int u = 0; u < 8; ++u) {
            float e0 = exp2f(sa0[2 * u]);
            float e1 = exp2f(sa0[2 * u + 1]);
            float f0 = exp2f(sa1[2 * u]);
            float f1 = exp2f(sa1[2 * u + 1]);
            psum += (e0 + e1) + (f0 + f1);
            ph0[u] = pk2(e0, e1);
            ph1[u] = pk2(f0, f1);
        }
        l_run += psum;

        // ---- O^T += V^T · P^T  (P^T B-frags via half-swap shuffles)
#pragma unroll
        for (int ks = 0; ks < 4; ++ks) {
            const u32* PH = (ks < 2) ? ph0 : ph1;
            const int ks2 = ks & 1;
            const int oi = 4 * ks2 + 2 * Hh;
            const int si = 4 * ks2 + 2 * (1 - Hh);
            u32 rh0 = __shfl_xor(PH[si], 32), rh1 = __shfl_xor(PH[si + 1], 32);
            union { u32 u[4]; frag8 f; } fh;
            if (Hh == 0) {
                fh.u[0] = PH[oi]; fh.u[1] = PH[oi + 1]; fh.u[2] = rh0; fh.u[3] = rh1;
            } else {
                fh.u[0] = rh0; fh.u[1] = rh1; fh.u[2] = PH[oi]; fh.u[3] = PH[oi + 1];
            }
            frag8 v0 = *(const frag8*)&sV[(ks * 64 + lane) * 8];
            frag8 v1 = *(const frag8*)&sV[((4 + ks) * 64 + lane) * 8];
            O0 = __builtin_amdgcn_mfma_f32_32x32x16_bf16(v0, fh.f, O0, 0, 0, 0);
            O1 = __builtin_amdgcn_mfma_f32_32x32x16_bf16(v1, fh.f, O1, 0, 0, 0);
        }
    }

    // ---- merge the two key-groups (plain sums; no m)
    l_run += __shfl_xor(l_run, 32);
    const int qr = wl * 32 + nq;
    if (Hh == 0) lsum[g][qr] = l_run;
    __syncthreads();                   // all stg reads done; union reuse safe
    const float invl = 1.f / (lsum[0][qr] + lsum[1][qr]);

    if (g == 1) {
#pragma unroll
        for (int cdh = 0; cdh < 2; ++cdh)
#pragma unroll
            for (int rg = 0; rg < 4; ++rg) {
                const f32x16& O = cdh ? O1 : O0;
                float4 v4;
                v4.x = O[4 * rg + 0]; v4.y = O[4 * rg + 1];
                v4.z = O[4 * rg + 2]; v4.w = O[4 * rg + 3];
                *(float4*)&L.xch[qr][cdh * 32 + rg * 8 + Hh * 4] = v4;
            }
    }
    __syncthreads();
    if (g == 0) {
#pragma unroll
        for (int cdh = 0; cdh < 2; ++cdh)
#pragma unroll
            for (int rg = 0; rg < 4; ++rg) {
                float4 p4 = *(const float4*)&L.xch[qr][cdh * 32 + rg * 8 + Hh * 4];
                const f32x16& O = cdh ? O1 : O0;
                float4 v4;
                v4.x = (O[4 * rg + 0] + p4.x) * invl;
                v4.y = (O[4 * rg + 1] + p4.y) * invl;
                v4.z = (O[4 * rg + 2] + p4.z) * invl;
                v4.w = (O[4 * rg + 3] + p4.w) * invl;
                *(float4*)&L.xch[qr][cdh * 32 + rg * 8 + Hh * 4] = v4;
            }
    }
    __syncthreads();
#pragma unroll
    for (int pass = 0; pass < 4; ++pass) {
        const int chunk = pass * 512 + tid;          // 0..2047
        const int qi = chunk >> 4, seg = chunk & 15;
        float4 v4 = *(const float4*)&L.xch[qi][seg * 4];
        u32 h01 = pk2(v4.x, v4.y), h23 = pk2(v4.z, v4.w);
        const size_t base = ((size_t)(b * S + qt * 128 + qi)) * D + h * DH + seg * 4;
        *(uint2*)&cth[base] = make_uint2(h01, h23);
        *(uint2*)&ctl[base] = make_uint2(pk2(v4.x - unpk_lo(h01), v4.y - unpk_hi(h01)),
                                         pk2(v4.z - unpk_lo(h23), v4.w - unpk_hi(h23)));
    }
}

// ---------------------------------------------------------------------------
// gemm_out: out[s][d] = sum_k ctx[s,k]*Wo[k,d] + bo. A=cth+ctl split, B=Wt+3072.
// 128x64 tile, grid (32,16).
// ---------------------------------------------------------------------------
__global__ __launch_bounds__(256, 4) void gemm_out(
    const u16* __restrict__ Ah, const u16* __restrict__ Al,
    const u16* __restrict__ Bh, const float* __restrict__ bo,
    float* __restrict__ out)
{
    const int r0  = blockIdx.x * 128;     // s
    const int c0  = blockIdx.y * 64;      // d
    const int tid = threadIdx.x;
    const int w = tid >> 6, lane = tid & 63;
    const int ml = lane & 15, kg = lane >> 4;

    __shared__ u16 Ta[2][128 * 32];
    __shared__ u16 Tl[2][128 * 32];
    __shared__ u16 Tb[2][64 * 32];

    const int srow = lane >> 2, sseg = lane & 3;
    const u16* Ag = Ah + (size_t)(r0 + w * 32 + srow) * 1024 + sseg * 8;
    const u16* Lg = Al + (size_t)(r0 + w * 32 + srow) * 1024 + sseg * 8;
    const u16* Bg = Bh + (size_t)(c0 + w * 16 + srow) * 1024 + sseg * 8;

    f32x4 acc[2][4];
#pragma unroll
    for (int i = 0; i < 2; ++i)
#pragma unroll
        for (int j = 0; j < 4; ++j)
#pragma unroll
            for (int r = 0; r < 4; ++r) acc[i][j][r] = 0.f;

    for (int k0 = 0; k0 < 1024; k0 += 64) {
        __syncthreads();
#pragma unroll
        for (int hb = 0; hb < 2; ++hb) {
            const int ko = k0 + hb * 32;
            glds16(Ag + ko,             &Ta[hb][(w * 32) * 32]);
            glds16(Ag + 16 * 1024 + ko, &Ta[hb][(w * 32 + 16) * 32]);
            glds16(Lg + ko,             &Tl[hb][(w * 32) * 32]);
            glds16(Lg + 16 * 1024 + ko, &Tl[hb][(w * 32 + 16) * 32]);
            glds16(Bg + ko,             &Tb[hb][(w * 16) * 32]);
        }
        __syncthreads();

#pragma unroll
        for (int hb = 0; hb < 2; ++hb) {
            frag8 af[2], lf[2], bf[4];
#pragma unroll
            for (int i = 0; i < 2; ++i) {
                af[i] = *(const frag8*)&Ta[hb][(w * 32 + i * 16 + ml) * 32 + kg * 8];
                lf[i] = *(const frag8*)&Tl[hb][(w * 32 + i * 16 + ml) * 32 + kg * 8];
            }
#pragma unroll
            for (int j = 0; j < 4; ++j)
                bf[j] = *(const frag8*)&Tb[hb][(j * 16 + ml) * 32 + kg * 8];
#pragma unroll
            for (int i = 0; i < 2; ++i)
#pragma unroll
                for (int j = 0; j < 4; ++j) {
                    acc[i][j] = __builtin_amdgcn_mfma_f32_16x16x32_bf16(af[i], bf[j], acc[i][j], 0, 0, 0);
                    acc[i][j] = __builtin_amdgcn_mfma_f32_16x16x32_bf16(lf[i], bf[j], acc[i][j], 0, 0, 0);
                }
        }
    }

#pragma unroll
    for (int i = 0; i < 2; ++i) {
        const int R0 = r0 + w * 32 + i * 16 + kg * 4;
#pragma unroll
        for (int j = 0; j < 4; ++j) {
            const int col = c0 + j * 16 + ml;
            const float bval = bo[col];
#pragma unroll
            for (int r = 0; r < 4; ++r)
                out[(size_t)(R0 + r) * 1024 + col] = acc[i][j][r] + bval;
        }
    }
}

// ---------------------------------------------------------------------------
extern "C" void kernel_launch(void* const* d_in, const int* in_sizes, int n_in,
                              void* d_out, int out_size, void* d_ws, size_t ws_size,
                              hipStream_t stream) {
    (void)in_sizes; (void)n_in; (void)out_size; (void)ws_size;
    const float* x  = (const float*)d_in[0];
    const float* Wq = (const float*)d_in[1];
    const float* bq = (const float*)d_in[2];
    const float* Wk = (const float*)d_in[3];
    const float* bk = (const float*)d_in[4];
    const float* Wv = (const float*)d_in[5];
    const float* bv = (const float*)d_in[6];
    const float* Wo = (const float*)d_in[7];
    const float* bo = (const float*)d_in[8];
    float* out = (float*)d_out;

    // Workspace: 6 x NPER u16 = 50.3 MB.
    //   xh,xl -> dead after gemm_qkv -> cth,ctl (attention output overlay)
    const size_t NPER = (size_t)BS * D;              // 4,194,304
    u16* base = (u16*)d_ws;
    u16* xh  = base;
    u16* xl  = base + NPER;
    u16* Wt  = base + 2 * NPER;
    u16* qh  = base + 3 * NPER;
    u16* khF = base + 4 * NPER;
    u16* vhF = base + 5 * NPER;
    u16* cth = xh;                                   // overlays xh
    u16* ctl = xl;                                   // overlays xl

    convert_x  <<<dim3(BS * D / 1024), 256, 0, stream>>>(x, xh, xl);
    transpose_w<<<dim3(16, 64),        256, 0, stream>>>(Wq, Wk, Wv, Wo, Wt);
    gemm_qkv   <<<dim3(24, 32), 256, 0, stream>>>(Wt, xh, xl, bq, bk, bv,
                                                  qh, khF, vhF);
    attention_mfma<<<dim3(512), 512, 0, stream>>>(qh, khF, vhF, cth, ctl);
    gemm_out   <<<dim3(32, 16), 256, 0, stream>>>(cth, ctl, Wt + (size_t)3072 * 1024,
                                                  bo, out);
}